// Round 6
// baseline (242.684 us; speedup 1.0000x reference)
//
#include <hip/hip_runtime.h>
#include <hip/hip_bf16.h>
#include <math.h>

#define B_ 32
#define S_ 1024
#define E_ 512
#define T_ 128
#define Q_ 256
#define H_ 4
#define F_ (H_ * Q_)      // 1024
#define M_ (B_ * S_)      // 32768

typedef __bf16 bf16x8 __attribute__((ext_vector_type(8)));
typedef float f32x4 __attribute__((ext_vector_type(4)));
typedef float f32x16 __attribute__((ext_vector_type(16)));
typedef unsigned int uint32;

__device__ __forceinline__ float lrelu(float x) { return x > 0.0f ? x : 0.01f * x; }
__device__ __forceinline__ uint32 pack_hi2(float a, float b) {
    return (__float_as_uint(a) >> 16) | (__float_as_uint(b) & 0xffff0000u);
}
__device__ __forceinline__ float resid(float f) {
    return f - __uint_as_float(__float_as_uint(f) & 0xffff0000u);
}

#define GLOAD_LDS16(g, l)                                                       \
    __builtin_amdgcn_global_load_lds(                                           \
        (const __attribute__((address_space(1))) void*)(g),                     \
        (__attribute__((address_space(3))) void*)(l), 16, 0, 0)

#define SRC_BLOCKS 16384      // src windows / 16
#define W_BLOCKS   512        // W_src windows / 16
#define HS_BLOCKS  1024       // head-select: wave per (t,b), 4 waves/block

// ---------------------------------------------------------------------------
// Fused prep: repack src/W_src in place (hi/lo bf16 per 64-float window) +
// per-(t,b) argmax head into best[] (dense, no atomics).
// ---------------------------------------------------------------------------
__global__ __launch_bounds__(256) void prep_kernel(
    float* src, float* wsrc,
    const float* __restrict__ qv, const float* __restrict__ Wopt,
    int* __restrict__ best) {
    const int blk = blockIdx.x;
    if (blk < SRC_BLOCKS + W_BLOCKS) {
        float* base = (blk < SRC_BLOCKS) ? src : wsrc;
        const size_t woff = (size_t)((blk < SRC_BLOCKS) ? blk : (blk - SRC_BLOCKS)) * 16;
        const int tid = threadIdx.x;
        const size_t c = woff + (tid >> 4);
        const int j = tid & 15;
        float* wp = base + c * 64;
        float4 v = *(const float4*)(wp + j * 4);
        uint32 h0 = pack_hi2(v.x, v.y), h1 = pack_hi2(v.z, v.w);
        uint32 l0 = pack_hi2(resid(v.x), resid(v.y));
        uint32 l1 = pack_hi2(resid(v.z), resid(v.w));
        *(uint2*)((char*)wp + j * 8)       = make_uint2(h0, h1);
        *(uint2*)((char*)wp + 128 + j * 8) = make_uint2(l0, l1);
    } else {
        const int wave = threadIdx.x >> 6, lane = threadIdx.x & 63;
        const int idx = (blk - SRC_BLOCKS - W_BLOCKS) * 4 + wave;   // t*B + b
        const float4 qq = *(const float4*)(qv + (size_t)idx * Q_ + lane * 4);
        float s[4];
#pragma unroll
        for (int h = 0; h < 4; ++h) {
            float4 w = *(const float4*)(Wopt + h * Q_ + lane * 4);
            s[h] = qq.x * w.x + qq.y * w.y + qq.z * w.z + qq.w * w.w;
        }
#pragma unroll
        for (int off = 32; off >= 1; off >>= 1) {
#pragma unroll
            for (int h = 0; h < 4; ++h) s[h] += __shfl_down(s[h], off);
        }
        if (lane == 0) {
            int bh = 0; float bs = s[0];
            if (s[1] > bs) { bs = s[1]; bh = 1; }
            if (s[2] > bs) { bs = s[2]; bh = 2; }
            if (s[3] > bs) { bs = s[3]; bh = 3; }
            best[idx] = bh;
        }
    }
}

// ---------------------------------------------------------------------------
// Fused proj+score. 1-D grid, XCD-swizzled: xcd = bid&7 keeps all 8 bj-tiles
// of one A-strip on one XCD (A fetched from HBM once, then L2).
// K-loop: split-bf16 3-MFMA via 32x32x16 (higher matrix rate, half the
// instruction count). Epilogue: local t-list from best[], split 16x16 score
// MFMA, plain stores to per-q-half buffers.
// ---------------------------------------------------------------------------
__global__ __launch_bounds__(256, 2) void proj_score_kernel(
    const unsigned char* __restrict__ Apk,   // repacked src
    const unsigned char* __restrict__ Wpk,   // repacked W_src
    const float* __restrict__ qv,            // (T,B,Q) fp32
    const int* __restrict__ best,            // (T*B)
    float* __restrict__ bufs)                // 2 x (T,B,S) in ws
{
    __shared__ uint4 smem4[4096];            // 64 KB
    char* smem = (char*)smem4;
    // K-loop:   Ah [0,16K) Al [16K,32K) Bh [32K,48K) Bl [48K,64K)
    // Epilogue: Ph [0,16K) Pl [16K,32K) Qh [32K,40K) Ql [40K,48K)
    //           tl [48K,+512) lcnt @48K+512

    // XCD-aware decode: assume xcd = blockIdx.x % 8 (perf heuristic only)
    const int bid = blockIdx.x;
    const int xcd = bid & 7;
    const int q_ = bid >> 3;                 // 0..255 within XCD
    const int bi = xcd * 32 + (q_ >> 3);     // 0..255 (M tile)
    const int bj = q_ & 7;                   // 0..7   (N tile)

    const int tid = threadIdx.x;
    const int wave = tid >> 6, lane = tid & 63;
    const int wm = wave >> 1, wn = wave & 1;
    const int l31 = lane & 31;
    const int khalf = lane >> 5;             // k-half for 32x32 frags
    const int quad = lane >> 4;              // for 16x16 score MFMA
    const int fr = lane & 15;
    const int xr = fr & 7;

    const int srow = lane >> 3;
    const int sgg = ((lane & 7) ^ srow) * 16;

    const size_t Abase = (size_t)(bi * 128) * 2048;
    const size_t Wbase = (size_t)(bj * 128) * 2048;

    f32x16 acc[2][2] = {};

    for (int kc = 0; kc < 8; ++kc) {
        const size_t koff = (size_t)kc * 256;
        __syncthreads();
#pragma unroll
        for (int c = 0; c < 4; ++c) {
            int chunk = wave * 4 + c;
            int row = chunk * 8 + srow;
            const unsigned char* ga = Apk + Abase + (size_t)row * 2048 + koff + sgg;
            const unsigned char* gw = Wpk + Wbase + (size_t)row * 2048 + koff + sgg;
            GLOAD_LDS16(ga,       smem +     chunk * 1024);
            GLOAD_LDS16(ga + 128, smem + 16384 + chunk * 1024);
            GLOAD_LDS16(gw,       smem + 32768 + chunk * 1024);
            GLOAD_LDS16(gw + 128, smem + 49152 + chunk * 1024);
        }
        __syncthreads();
#pragma unroll
        for (int kk = 0; kk < 4; ++kk) {
            // logical 16B granule for this lane's k-half of the k16 slice
            const int ko = (((kk * 2 + khalf) ^ (lane & 7)) & 7) * 16;
            bf16x8 ah[2], al[2], bh[2], bl[2];
#pragma unroll
            for (int i = 0; i < 2; ++i) {
                int ra = wm * 64 + i * 32 + l31;
                int rb = wn * 64 + i * 32 + l31;
                ah[i] = *(const bf16x8*)(smem +         ra * 128 + ko);
                al[i] = *(const bf16x8*)(smem + 16384 + ra * 128 + ko);
                bh[i] = *(const bf16x8*)(smem + 32768 + rb * 128 + ko);
                bl[i] = *(const bf16x8*)(smem + 49152 + rb * 128 + ko);
            }
#pragma unroll
            for (int i = 0; i < 2; ++i)
#pragma unroll
                for (int j = 0; j < 2; ++j) {
                    acc[i][j] = __builtin_amdgcn_mfma_f32_32x32x16_bf16(ah[i], bh[j], acc[i][j], 0, 0, 0);
                    acc[i][j] = __builtin_amdgcn_mfma_f32_32x32x16_bf16(ah[i], bl[j], acc[i][j], 0, 0, 0);
                    acc[i][j] = __builtin_amdgcn_mfma_f32_32x32x16_bf16(al[i], bh[j], acc[i][j], 0, 0, 0);
                }
        }
    }

    // ---- fused score epilogue ----
    const int b = bi >> 3;
    const int sbase = (bi & 7) * 128;
    const int h = bj >> 1;
    const int qoff = (bj & 1) * 128;
    float* buf = bufs + (size_t)(bj & 1) * ((size_t)T_ * B_ * S_);

    __syncthreads();                       // K-loop LDS reads done
    int* tl = (int*)(smem + 49152);
    int* lcnt = (int*)(smem + 49152 + 512);
    if (tid == 0) *lcnt = 0;
    __syncthreads();
    if (tid < 128) {
        if (best[tid * B_ + b] == h) {
            int slot = atomicAdd(lcnt, 1);   // LDS atomic
            tl[slot] = tid;
        }
    }
    __syncthreads();
    const int n = *lcnt;

    const int t_idx = tid >> 3, seg = tid & 7;

    for (int half = 0; half < 2; ++half) {
        if (wm == half) {
            // write 2x2x16 acc (32x32 C-layout) as hi/lo bf16 rows (s-local)
#pragma unroll
            for (int i = 0; i < 2; ++i) {
#pragma unroll
                for (int j = 0; j < 2; ++j) {
                    int col = wn * 64 + j * 32 + l31;
                    int g = col >> 3;
                    int cb = (col & 7) * 2;
#pragma unroll
                    for (int reg = 0; reg < 16; ++reg) {
                        int rr = i * 32 + (reg & 3) + 8 * (reg >> 2) + 4 * khalf;
                        int gs = (g & 8) | ((g ^ rr) & 7);
                        float v = lrelu(acc[i][j][reg]);
                        uint32 u = __float_as_uint(v);
                        *(unsigned short*)(smem +         rr * 256 + gs * 16 + cb) = (unsigned short)(u >> 16);
                        float lo = v - __uint_as_float(u & 0xffff0000u);
                        *(unsigned short*)(smem + 16384 + rr * 256 + gs * 16 + cb) =
                            (unsigned short)(__float_as_uint(lo) >> 16);
                    }
                }
            }
        }
        __syncthreads();

        for (int tc = 0; tc < n; tc += 32) {
            int nn = min(32, n - tc);
            if (t_idx < nn) {
                int tt = tl[tc + t_idx];
                const float* qp = qv + ((size_t)tt * B_ + b) * Q_ + qoff + seg * 16;
                float4 f0 = *(const float4*)(qp);
                float4 f1 = *(const float4*)(qp + 4);
                float4 f2 = *(const float4*)(qp + 8);
                float4 f3 = *(const float4*)(qp + 12);
                uint4 h0 = make_uint4(pack_hi2(f0.x, f0.y), pack_hi2(f0.z, f0.w),
                                      pack_hi2(f1.x, f1.y), pack_hi2(f1.z, f1.w));
                uint4 h1 = make_uint4(pack_hi2(f2.x, f2.y), pack_hi2(f2.z, f2.w),
                                      pack_hi2(f3.x, f3.y), pack_hi2(f3.z, f3.w));
                uint4 l0 = make_uint4(pack_hi2(resid(f0.x), resid(f0.y)), pack_hi2(resid(f0.z), resid(f0.w)),
                                      pack_hi2(resid(f1.x), resid(f1.y)), pack_hi2(resid(f1.z), resid(f1.w)));
                uint4 l1 = make_uint4(pack_hi2(resid(f2.x), resid(f2.y)), pack_hi2(resid(f2.z), resid(f2.w)),
                                      pack_hi2(resid(f3.x), resid(f3.y)), pack_hi2(resid(f3.z), resid(f3.w)));
                int g0 = seg * 2, g1 = seg * 2 + 1;
                int gs0 = (g0 & 8) | ((g0 ^ t_idx) & 7);
                int gs1 = (g1 & 8) | ((g1 ^ t_idx) & 7);
                *(uint4*)(smem + 32768 + t_idx * 256 + gs0 * 16) = h0;
                *(uint4*)(smem + 32768 + t_idx * 256 + gs1 * 16) = h1;
                *(uint4*)(smem + 40960 + t_idx * 256 + gs0 * 16) = l0;
                *(uint4*)(smem + 40960 + t_idx * 256 + gs1 * 16) = l1;
            }
            __syncthreads();

            f32x4 sc0 = {0.f, 0.f, 0.f, 0.f}, sc1 = {0.f, 0.f, 0.f, 0.f};
#pragma unroll
            for (int ks = 0; ks < 4; ++ks) {
                int kb = ks * 4 + quad;
                int ko = ((kb & 8) | ((kb ^ xr) & 7)) * 16;
                int prow = wave * 16 + fr;
                bf16x8 ph = *(const bf16x8*)(smem +         prow * 256 + ko);
                bf16x8 pl = *(const bf16x8*)(smem + 16384 + prow * 256 + ko);
                bf16x8 qh0 = *(const bf16x8*)(smem + 32768 + fr * 256 + ko);
                bf16x8 ql0 = *(const bf16x8*)(smem + 40960 + fr * 256 + ko);
                sc0 = __builtin_amdgcn_mfma_f32_16x16x32_bf16(qh0, ph, sc0, 0, 0, 0);
                sc0 = __builtin_amdgcn_mfma_f32_16x16x32_bf16(qh0, pl, sc0, 0, 0, 0);
                sc0 = __builtin_amdgcn_mfma_f32_16x16x32_bf16(ql0, ph, sc0, 0, 0, 0);
                if (nn > 16) {
                    bf16x8 qh1 = *(const bf16x8*)(smem + 32768 + (16 + fr) * 256 + ko);
                    bf16x8 ql1 = *(const bf16x8*)(smem + 40960 + (16 + fr) * 256 + ko);
                    sc1 = __builtin_amdgcn_mfma_f32_16x16x32_bf16(qh1, ph, sc1, 0, 0, 0);
                    sc1 = __builtin_amdgcn_mfma_f32_16x16x32_bf16(qh1, pl, sc1, 0, 0, 0);
                    sc1 = __builtin_amdgcn_mfma_f32_16x16x32_bf16(ql1, ph, sc1, 0, 0, 0);
                }
            }
            int sg = sbase + half * 64 + wave * 16 + fr;
#pragma unroll
            for (int r = 0; r < 4; ++r) {
                int t0 = quad * 4 + r;
                if (t0 < nn) {
                    int tg = tl[tc + t0];
                    buf[((size_t)tg * B_ + b) * S_ + sg] = sc0[r];
                }
                int t1 = 16 + quad * 4 + r;
                if (t1 < nn) {
                    int tg = tl[tc + t1];
                    buf[((size_t)tg * B_ + b) * S_ + sg] = sc1[r];
                }
            }
            __syncthreads();
        }
        __syncthreads();
    }
}

// ---------------------------------------------------------------------------
// Masked softmax: logits = buf0 + buf1 (q-half partials), masked, softmax.
// ---------------------------------------------------------------------------
__global__ __launch_bounds__(256) void softmax_kernel(
    const float* __restrict__ bufs, float* __restrict__ out,
    const int* __restrict__ mask) {
    const int row = blockIdx.x;
    const int b = row & (B_ - 1);
    const float* w0 = bufs + (size_t)row * S_;
    const float* w1 = w0 + (size_t)T_ * B_ * S_;
    float* w = out + (size_t)row * S_;
    const int* mrow = mask + (size_t)b * S_;
    const int tid = threadIdx.x;

    float4 va = *(const float4*)(w0 + tid * 4);
    float4 vb = *(const float4*)(w1 + tid * 4);
    int4 mm = *(const int4*)(mrow + tid * 4);
    float x0 = mm.x ? -INFINITY : (va.x + vb.x);
    float x1 = mm.y ? -INFINITY : (va.y + vb.y);
    float x2 = mm.z ? -INFINITY : (va.z + vb.z);
    float x3 = mm.w ? -INFINITY : (va.w + vb.w);

    float lmax = fmaxf(fmaxf(x0, x1), fmaxf(x2, x3));
#pragma unroll
    for (int off = 32; off >= 1; off >>= 1)
        lmax = fmaxf(lmax, __shfl_down(lmax, off));

    __shared__ float redmax[4];
    __shared__ float redsum[4];
    const int wave = tid >> 6, lane = tid & 63;
    if (lane == 0) redmax[wave] = lmax;
    __syncthreads();
    float gmax = fmaxf(fmaxf(redmax[0], redmax[1]), fmaxf(redmax[2], redmax[3]));

    float e0 = mm.x ? 0.f : __expf(x0 - gmax);
    float e1 = mm.y ? 0.f : __expf(x1 - gmax);
    float e2 = mm.z ? 0.f : __expf(x2 - gmax);
    float e3 = mm.w ? 0.f : __expf(x3 - gmax);
    float lsum = e0 + e1 + e2 + e3;
#pragma unroll
    for (int off = 32; off >= 1; off >>= 1)
        lsum += __shfl_down(lsum, off);
    if (lane == 0) redsum[wave] = lsum;
    __syncthreads();
    float gsum = redsum[0] + redsum[1] + redsum[2] + redsum[3];
    float rinv = 1.0f / gsum;

    *(float4*)(w + tid * 4) = make_float4(e0 * rinv, e1 * rinv, e2 * rinv, e3 * rinv);
}

// ---------------------------------------------------------------------------
extern "C" void kernel_launch(void* const* d_in, const int* in_sizes, int n_in,
                              void* d_out, int out_size, void* d_ws, size_t ws_size,
                              hipStream_t stream) {
    float* src  = (float*)d_in[0];               // (B,S,E) — repacked in-place
    const int* mask = (const int*)d_in[1];       // (B,S)
    const float* qv = (const float*)d_in[2];     // (T,B,Q) fp32
    float* Wsrc = (float*)d_in[3];               // (H*Q,E) — repacked in-place
    const float* Wopt = (const float*)d_in[4];   // (H,Q)
    float* out = (float*)d_out;                  // (T,B,S)

    // ws: bufs = 2 x 16 MiB score partials, then best[] (T*B ints)
    float* bufs = (float*)d_ws;
    int* best = (int*)((char*)d_ws + 2 * (size_t)T_ * B_ * S_ * sizeof(float));

    hipLaunchKernelGGL(prep_kernel, dim3(SRC_BLOCKS + W_BLOCKS + HS_BLOCKS), dim3(256),
                       0, stream, src, Wsrc, qv, Wopt, best);
    hipLaunchKernelGGL(proj_score_kernel, dim3(2048), dim3(256), 0, stream,
                       (const unsigned char*)src, (const unsigned char*)Wsrc,
                       qv, best, bufs);
    hipLaunchKernelGGL(softmax_kernel, dim3(T_ * B_), dim3(256), 0, stream,
                       bufs, out, mask);
}

// Round 7
// 227.442 us; speedup vs baseline: 1.0670x; 1.0670x over previous
//
#include <hip/hip_runtime.h>
#include <hip/hip_bf16.h>
#include <math.h>

#define B_ 32
#define S_ 1024
#define E_ 512
#define T_ 128
#define Q_ 256
#define H_ 4
#define F_ (H_ * Q_)      // 1024
#define M_ (B_ * S_)      // 32768

typedef __bf16 bf16x8 __attribute__((ext_vector_type(8)));
typedef float f32x4 __attribute__((ext_vector_type(4)));
typedef unsigned int uint32;

__device__ __forceinline__ float lrelu(float x) { return x > 0.0f ? x : 0.01f * x; }
__device__ __forceinline__ uint32 pack_hi2(float a, float b) {
    return (__float_as_uint(a) >> 16) | (__float_as_uint(b) & 0xffff0000u);
}
__device__ __forceinline__ float resid(float f) {
    return f - __uint_as_float(__float_as_uint(f) & 0xffff0000u);
}

#define GLOAD_LDS16(g, l)                                                       \
    __builtin_amdgcn_global_load_lds(                                           \
        (const __attribute__((address_space(1))) void*)(g),                     \
        (__attribute__((address_space(3))) void*)(l), 16, 0, 0)

#define SRC_BLOCKS 16384      // src windows / 16
#define W_BLOCKS   512        // W_src windows / 16
#define HS_BLOCKS  1024       // head-select: wave per (t,b), 4 waves/block

// ---------------------------------------------------------------------------
// Fused prep: repack src/W_src in place (hi/lo bf16 per 64-float window) +
// per-(t,b) argmax head into best[] (dense, no atomics).
// ---------------------------------------------------------------------------
__global__ __launch_bounds__(256) void prep_kernel(
    float* src, float* wsrc,
    const float* __restrict__ qv, const float* __restrict__ Wopt,
    int* __restrict__ best) {
    const int blk = blockIdx.x;
    if (blk < SRC_BLOCKS + W_BLOCKS) {
        float* base = (blk < SRC_BLOCKS) ? src : wsrc;
        const size_t woff = (size_t)((blk < SRC_BLOCKS) ? blk : (blk - SRC_BLOCKS)) * 16;
        const int tid = threadIdx.x;
        const size_t c = woff + (tid >> 4);
        const int j = tid & 15;
        float* wp = base + c * 64;
        float4 v = *(const float4*)(wp + j * 4);
        uint32 h0 = pack_hi2(v.x, v.y), h1 = pack_hi2(v.z, v.w);
        uint32 l0 = pack_hi2(resid(v.x), resid(v.y));
        uint32 l1 = pack_hi2(resid(v.z), resid(v.w));
        *(uint2*)((char*)wp + j * 8)       = make_uint2(h0, h1);
        *(uint2*)((char*)wp + 128 + j * 8) = make_uint2(l0, l1);
    } else {
        const int wave = threadIdx.x >> 6, lane = threadIdx.x & 63;
        const int idx = (blk - SRC_BLOCKS - W_BLOCKS) * 4 + wave;   // t*B + b
        const float4 qq = *(const float4*)(qv + (size_t)idx * Q_ + lane * 4);
        float s[4];
#pragma unroll
        for (int h = 0; h < 4; ++h) {
            float4 w = *(const float4*)(Wopt + h * Q_ + lane * 4);
            s[h] = qq.x * w.x + qq.y * w.y + qq.z * w.z + qq.w * w.w;
        }
#pragma unroll
        for (int off = 32; off >= 1; off >>= 1) {
#pragma unroll
            for (int h = 0; h < 4; ++h) s[h] += __shfl_down(s[h], off);
        }
        if (lane == 0) {
            int bh = 0; float bs = s[0];
            if (s[1] > bs) { bs = s[1]; bh = 1; }
            if (s[2] > bs) { bs = s[2]; bh = 2; }
            if (s[3] > bs) { bs = s[3]; bh = 3; }
            best[idx] = bh;
        }
    }
}

// ---------------------------------------------------------------------------
// Fused proj+score. 1-D grid, XCD-swizzled (xcd = bid&7): all 8 bj-tiles of
// one A-strip land on one XCD -> A fetched from HBM once (proved r6:
// FETCH 268->59 MB). K-loop: 16x16x32 split-bf16 3-MFMA (the 16x16 frag-read
// pattern is the only one compatible with the XOR swizzle on 128B rows —
// 32x32 frags force structural 4-way conflicts, measured r6). Epilogue:
// local t-list from best[], split score MFMA, plain stores to q-half bufs.
// ---------------------------------------------------------------------------
__global__ __launch_bounds__(256, 2) void proj_score_kernel(
    const unsigned char* __restrict__ Apk,   // repacked src
    const unsigned char* __restrict__ Wpk,   // repacked W_src
    const float* __restrict__ qv,            // (T,B,Q) fp32
    const int* __restrict__ best,            // (T*B)
    float* __restrict__ bufs)                // 2 x (T,B,S) in ws
{
    __shared__ uint4 smem4[4096];            // 64 KB
    char* smem = (char*)smem4;
    // K-loop:   Ah [0,16K) Al [16K,32K) Bh [32K,48K) Bl [48K,64K)
    // Epilogue: Ph [0,16K) Pl [16K,32K) Qh [32K,40K) Ql [40K,48K)
    //           tl [48K,+512) lcnt @48K+512

    const int bid = blockIdx.x;
    const int xcd = bid & 7;
    const int q_ = bid >> 3;                 // 0..255 within XCD
    const int bi = xcd * 32 + (q_ >> 3);     // 0..255 (M tile)
    const int bj = q_ & 7;                   // 0..7   (N tile)

    const int tid = threadIdx.x;
    const int wave = tid >> 6, lane = tid & 63;
    const int wm = wave >> 1, wn = wave & 1;
    const int quad = lane >> 4;
    const int fr = lane & 15;
    const int xr = fr & 7;

    const int srow = lane >> 3;
    const int sgg = ((lane & 7) ^ srow) * 16;

    const size_t Abase = (size_t)(bi * 128) * 2048;
    const size_t Wbase = (size_t)(bj * 128) * 2048;

    const int ko0 = ((quad ^ xr) & 7) * 16;
    const int ko1 = (((quad ^ 4) ^ xr) & 7) * 16;

    f32x4 acc[4][4] = {};

    for (int kc = 0; kc < 8; ++kc) {
        const size_t koff = (size_t)kc * 256;
        __syncthreads();
#pragma unroll
        for (int c = 0; c < 4; ++c) {
            int chunk = wave * 4 + c;
            int row = chunk * 8 + srow;
            const unsigned char* ga = Apk + Abase + (size_t)row * 2048 + koff + sgg;
            const unsigned char* gw = Wpk + Wbase + (size_t)row * 2048 + koff + sgg;
            GLOAD_LDS16(ga,       smem +     chunk * 1024);
            GLOAD_LDS16(ga + 128, smem + 16384 + chunk * 1024);
            GLOAD_LDS16(gw,       smem + 32768 + chunk * 1024);
            GLOAD_LDS16(gw + 128, smem + 49152 + chunk * 1024);
        }
        __syncthreads();
#pragma unroll
        for (int kk = 0; kk < 2; ++kk) {
            const int ko = kk ? ko1 : ko0;
            bf16x8 ah[4], al[4], bh[4], bl[4];
#pragma unroll
            for (int i = 0; i < 4; ++i) {
                int ra = wm * 64 + i * 16 + fr;
                int rb = wn * 64 + i * 16 + fr;
                ah[i] = *(const bf16x8*)(smem +         ra * 128 + ko);
                al[i] = *(const bf16x8*)(smem + 16384 + ra * 128 + ko);
                bh[i] = *(const bf16x8*)(smem + 32768 + rb * 128 + ko);
                bl[i] = *(const bf16x8*)(smem + 49152 + rb * 128 + ko);
            }
#pragma unroll
            for (int i = 0; i < 4; ++i)
#pragma unroll
                for (int j = 0; j < 4; ++j) {
                    acc[i][j] = __builtin_amdgcn_mfma_f32_16x16x32_bf16(ah[i], bh[j], acc[i][j], 0, 0, 0);
                    acc[i][j] = __builtin_amdgcn_mfma_f32_16x16x32_bf16(ah[i], bl[j], acc[i][j], 0, 0, 0);
                    acc[i][j] = __builtin_amdgcn_mfma_f32_16x16x32_bf16(al[i], bh[j], acc[i][j], 0, 0, 0);
                }
        }
    }

    // ---- fused score epilogue ----
    const int b = bi >> 3;
    const int sbase = (bi & 7) * 128;
    const int h = bj >> 1;
    const int qoff = (bj & 1) * 128;
    float* buf = bufs + (size_t)(bj & 1) * ((size_t)T_ * B_ * S_);

    __syncthreads();                       // K-loop LDS reads done
    int* tl = (int*)(smem + 49152);
    int* lcnt = (int*)(smem + 49152 + 512);
    if (tid == 0) *lcnt = 0;
    __syncthreads();
    if (tid < 128) {
        if (best[tid * B_ + b] == h) {
            int slot = atomicAdd(lcnt, 1);   // LDS atomic
            tl[slot] = tid;
        }
    }
    __syncthreads();
    const int n = *lcnt;

    const int t_idx = tid >> 3, seg = tid & 7;

    for (int half = 0; half < 2; ++half) {
        if (wm == half) {
#pragma unroll
            for (int i = 0; i < 4; ++i) {
#pragma unroll
                for (int j = 0; j < 4; ++j) {
                    int col = wn * 64 + j * 16 + fr;
                    int g = col >> 3;
                    int cb = (col & 7) * 2;
#pragma unroll
                    for (int r = 0; r < 4; ++r) {
                        int rr = i * 16 + quad * 4 + r;
                        int gs = (g & 8) | ((g ^ rr) & 7);
                        float v = lrelu(acc[i][j][r]);
                        uint32 u = __float_as_uint(v);
                        *(unsigned short*)(smem +         rr * 256 + gs * 16 + cb) = (unsigned short)(u >> 16);
                        float lo = v - __uint_as_float(u & 0xffff0000u);
                        *(unsigned short*)(smem + 16384 + rr * 256 + gs * 16 + cb) =
                            (unsigned short)(__float_as_uint(lo) >> 16);
                    }
                }
            }
        }
        __syncthreads();

        for (int tc = 0; tc < n; tc += 32) {
            int nn = min(32, n - tc);
            if (t_idx < nn) {
                int tt = tl[tc + t_idx];
                const float* qp = qv + ((size_t)tt * B_ + b) * Q_ + qoff + seg * 16;
                float4 f0 = *(const float4*)(qp);
                float4 f1 = *(const float4*)(qp + 4);
                float4 f2 = *(const float4*)(qp + 8);
                float4 f3 = *(const float4*)(qp + 12);
                uint4 h0 = make_uint4(pack_hi2(f0.x, f0.y), pack_hi2(f0.z, f0.w),
                                      pack_hi2(f1.x, f1.y), pack_hi2(f1.z, f1.w));
                uint4 h1 = make_uint4(pack_hi2(f2.x, f2.y), pack_hi2(f2.z, f2.w),
                                      pack_hi2(f3.x, f3.y), pack_hi2(f3.z, f3.w));
                uint4 l0 = make_uint4(pack_hi2(resid(f0.x), resid(f0.y)), pack_hi2(resid(f0.z), resid(f0.w)),
                                      pack_hi2(resid(f1.x), resid(f1.y)), pack_hi2(resid(f1.z), resid(f1.w)));
                uint4 l1 = make_uint4(pack_hi2(resid(f2.x), resid(f2.y)), pack_hi2(resid(f2.z), resid(f2.w)),
                                      pack_hi2(resid(f3.x), resid(f3.y)), pack_hi2(resid(f3.z), resid(f3.w)));
                int g0 = seg * 2, g1 = seg * 2 + 1;
                int gs0 = (g0 & 8) | ((g0 ^ t_idx) & 7);
                int gs1 = (g1 & 8) | ((g1 ^ t_idx) & 7);
                *(uint4*)(smem + 32768 + t_idx * 256 + gs0 * 16) = h0;
                *(uint4*)(smem + 32768 + t_idx * 256 + gs1 * 16) = h1;
                *(uint4*)(smem + 40960 + t_idx * 256 + gs0 * 16) = l0;
                *(uint4*)(smem + 40960 + t_idx * 256 + gs1 * 16) = l1;
            }
            __syncthreads();

            f32x4 sc0 = {0.f, 0.f, 0.f, 0.f}, sc1 = {0.f, 0.f, 0.f, 0.f};
#pragma unroll
            for (int ks = 0; ks < 4; ++ks) {
                int kb = ks * 4 + quad;
                int ko = ((kb & 8) | ((kb ^ xr) & 7)) * 16;
                int prow = wave * 16 + fr;
                bf16x8 ph = *(const bf16x8*)(smem +         prow * 256 + ko);
                bf16x8 pl = *(const bf16x8*)(smem + 16384 + prow * 256 + ko);
                bf16x8 qh0 = *(const bf16x8*)(smem + 32768 + fr * 256 + ko);
                bf16x8 ql0 = *(const bf16x8*)(smem + 40960 + fr * 256 + ko);
                sc0 = __builtin_amdgcn_mfma_f32_16x16x32_bf16(qh0, ph, sc0, 0, 0, 0);
                sc0 = __builtin_amdgcn_mfma_f32_16x16x32_bf16(qh0, pl, sc0, 0, 0, 0);
                sc0 = __builtin_amdgcn_mfma_f32_16x16x32_bf16(ql0, ph, sc0, 0, 0, 0);
                if (nn > 16) {
                    bf16x8 qh1 = *(const bf16x8*)(smem + 32768 + (16 + fr) * 256 + ko);
                    bf16x8 ql1 = *(const bf16x8*)(smem + 40960 + (16 + fr) * 256 + ko);
                    sc1 = __builtin_amdgcn_mfma_f32_16x16x32_bf16(qh1, ph, sc1, 0, 0, 0);
                    sc1 = __builtin_amdgcn_mfma_f32_16x16x32_bf16(qh1, pl, sc1, 0, 0, 0);
                    sc1 = __builtin_amdgcn_mfma_f32_16x16x32_bf16(ql1, ph, sc1, 0, 0, 0);
                }
            }
            int sg = sbase + half * 64 + wave * 16 + fr;
#pragma unroll
            for (int r = 0; r < 4; ++r) {
                int t0 = quad * 4 + r;
                if (t0 < nn) {
                    int tg = tl[tc + t0];
                    buf[((size_t)tg * B_ + b) * S_ + sg] = sc0[r];
                }
                int t1 = 16 + quad * 4 + r;
                if (t1 < nn) {
                    int tg = tl[tc + t1];
                    buf[((size_t)tg * B_ + b) * S_ + sg] = sc1[r];
                }
            }
            __syncthreads();
        }
        __syncthreads();
    }
}

// ---------------------------------------------------------------------------
// Masked softmax: logits = buf0 + buf1 (q-half partials), masked, softmax.
// ---------------------------------------------------------------------------
__global__ __launch_bounds__(256) void softmax_kernel(
    const float* __restrict__ bufs, float* __restrict__ out,
    const int* __restrict__ mask) {
    const int row = blockIdx.x;
    const int b = row & (B_ - 1);
    const float* w0 = bufs + (size_t)row * S_;
    const float* w1 = w0 + (size_t)T_ * B_ * S_;
    float* w = out + (size_t)row * S_;
    const int* mrow = mask + (size_t)b * S_;
    const int tid = threadIdx.x;

    float4 va = *(const float4*)(w0 + tid * 4);
    float4 vb = *(const float4*)(w1 + tid * 4);
    int4 mm = *(const int4*)(mrow + tid * 4);
    float x0 = mm.x ? -INFINITY : (va.x + vb.x);
    float x1 = mm.y ? -INFINITY : (va.y + vb.y);
    float x2 = mm.z ? -INFINITY : (va.z + vb.z);
    float x3 = mm.w ? -INFINITY : (va.w + vb.w);

    float lmax = fmaxf(fmaxf(x0, x1), fmaxf(x2, x3));
#pragma unroll
    for (int off = 32; off >= 1; off >>= 1)
        lmax = fmaxf(lmax, __shfl_down(lmax, off));

    __shared__ float redmax[4];
    __shared__ float redsum[4];
    const int wave = tid >> 6, lane = tid & 63;
    if (lane == 0) redmax[wave] = lmax;
    __syncthreads();
    float gmax = fmaxf(fmaxf(redmax[0], redmax[1]), fmaxf(redmax[2], redmax[3]));

    float e0 = mm.x ? 0.f : __expf(x0 - gmax);
    float e1 = mm.y ? 0.f : __expf(x1 - gmax);
    float e2 = mm.z ? 0.f : __expf(x2 - gmax);
    float e3 = mm.w ? 0.f : __expf(x3 - gmax);
    float lsum = e0 + e1 + e2 + e3;
#pragma unroll
    for (int off = 32; off >= 1; off >>= 1)
        lsum += __shfl_down(lsum, off);
    if (lane == 0) redsum[wave] = lsum;
    __syncthreads();
    float gsum = redsum[0] + redsum[1] + redsum[2] + redsum[3];
    float rinv = 1.0f / gsum;

    *(float4*)(w + tid * 4) = make_float4(e0 * rinv, e1 * rinv, e2 * rinv, e3 * rinv);
}

// ---------------------------------------------------------------------------
extern "C" void kernel_launch(void* const* d_in, const int* in_sizes, int n_in,
                              void* d_out, int out_size, void* d_ws, size_t ws_size,
                              hipStream_t stream) {
    float* src  = (float*)d_in[0];               // (B,S,E) — repacked in-place
    const int* mask = (const int*)d_in[1];       // (B,S)
    const float* qv = (const float*)d_in[2];     // (T,B,Q) fp32
    float* Wsrc = (float*)d_in[3];               // (H*Q,E) — repacked in-place
    const float* Wopt = (const float*)d_in[4];   // (H,Q)
    float* out = (float*)d_out;                  // (T,B,S)

    // ws: bufs = 2 x 16 MiB score partials, then best[] (T*B ints)
    float* bufs = (float*)d_ws;
    int* best = (int*)((char*)d_ws + 2 * (size_t)T_ * B_ * S_ * sizeof(float));

    hipLaunchKernelGGL(prep_kernel, dim3(SRC_BLOCKS + W_BLOCKS + HS_BLOCKS), dim3(256),
                       0, stream, src, Wsrc, qv, Wopt, best);
    hipLaunchKernelGGL(proj_score_kernel, dim3(2048), dim3(256), 0, stream,
                       (const unsigned char*)src, (const unsigned char*)Wsrc,
                       qv, best, bufs);
    hipLaunchKernelGGL(softmax_kernel, dim3(T_ * B_), dim3(256), 0, stream,
                       bufs, out, mask);
}